// Round 1
// baseline (875.662 us; speedup 1.0000x reference)
//
#include <hip/hip_runtime.h>
#include <hip/hip_cooperative_groups.h>
#include <stdint.h>
#include <stddef.h>

// IEEE-exact ops, no FMA contraction: must reproduce the reference's f32
// arithmetic (binary labels => exact label match, absmax 0).
#pragma clang fp contract(off)

namespace cg = cooperative_groups;

#define HH 512
#define WW 512
#define HW_ 262144             // H*W
#define FEAT_BSTRIDE (256*HW_) // feature batch stride (C=256)

__device__ __forceinline__ float quantf(float f, float mn, float denom) {
  float v = (f - mn) / denom * 255.0f;
  v = floorf(v);
  return fminf(fmaxf(v, 0.0f), 255.0f);
}

// trimap geometry: bh=bw=51, center rows/cols [230,281)
__device__ __forceinline__ bool is_center(int y, int x) {
  return (y >= 230) & (y < 281) & (x >= 230) & (x < 281);
}
__device__ __forceinline__ bool is_border(int y, int x) {
  return (y < 51) | (y >= 461) | (x < 51) | (x >= 461);
}

// Single cooperative kernel: minmax -> quantize(regs) -> 5 ICM iterations.
// Each block owns 2048 consecutive pixels for the whole kernel; the packed
// RGB stays in 8 VGPRs/thread, so no packed buffer in global memory at all.
// Cross-block data (alpha neighbors, reduction partials) goes through ws with
// __threadfence() + grid.sync() between phases.
__global__ __launch_bounds__(256) void k_fused(
    const float* __restrict__ feat, const int* __restrict__ mask,
    float* __restrict__ out,
    uint8_t* __restrict__ aA, uint8_t* __restrict__ aB,
    float2* __restrict__ mm, int4* __restrict__ totals,
    int4* __restrict__ slots)
{
  cg::grid_group grid = cg::this_grid();
  const int blk = blockIdx.x, tid = threadIdx.x;
  const int b = blk >> 7;
  const float* fbp = feat + (size_t)b * FEAT_BSTRIDE;

  __shared__ float smn[256], smx[256];
  __shared__ int red[256][8];
  __shared__ float fmv[3], bmv[3];

  // ---- phase A: load features into regs, per-block minmax, trimap codes ----
  float fr[8], fg[8], fbl[8];
  uint32_t code = 0;  // 2 bits/pixel: 1=fixed FG, 2=fixed BG, 3=mask-FG, 0=mask-BG
  float mn = 3.4e38f, mx = -3.4e38f;
#pragma unroll
  for (int j = 0; j < 8; j++) {
    int p = blk * 2048 + tid + j * 256;
    int pb = p & (HW_ - 1);
    int y = pb >> 9, x = pb & 511;
    float r = fbp[pb], g = fbp[HW_ + pb], bl = fbp[2 * HW_ + pb];
    fr[j] = r; fg[j] = g; fbl[j] = bl;
    mn = fminf(mn, fminf(r, fminf(g, bl)));
    mx = fmaxf(mx, fmaxf(r, fmaxf(g, bl)));
    uint32_t c2;
    if (is_center(y, x)) c2 = 1u;
    else if (is_border(y, x)) c2 = 2u;
    else c2 = (mask[p] == 1) ? 3u : 0u;
    code |= c2 << (2 * j);
  }
  smn[tid] = mn; smx[tid] = mx;
  __syncthreads();
  for (int s = 128; s >= 1; s >>= 1) {
    if (tid < s) {
      smn[tid] = fminf(smn[tid], smn[tid + s]);
      smx[tid] = fmaxf(smx[tid], smx[tid + s]);
    }
    __syncthreads();
  }
  if (tid == 0) mm[blk] = make_float2(smn[0], smx[0]);
  __threadfence();
  grid.sync();

  // ---- phase B: batch minmax reduce (redundant per block), quantize regs,
  //      init alpha, slot0 + totals partials ----
  if (tid < 128) { float2 v = mm[b * 128 + tid]; smn[tid] = v.x; smx[tid] = v.y; }
  __syncthreads();
  for (int s = 64; s >= 1; s >>= 1) {
    if (tid < s) {
      smn[tid] = fminf(smn[tid], smn[tid + s]);
      smx[tid] = fmaxf(smx[tid], smx[tid + s]);
    }
    __syncthreads();
  }
  float bmn = smn[0];
  float denom = (smx[0] - bmn) + 1e-12f;  // f32, matches reference

  uint32_t pk[8];
  {
    int a0 = 0, a1 = 0, a2 = 0, a3 = 0, t0 = 0, t1 = 0, t2 = 0;
#pragma unroll
    for (int j = 0; j < 8; j++) {
      int p = blk * 2048 + tid + j * 256;
      int r  = (int)quantf(fr[j],  bmn, denom);
      int g  = (int)quantf(fg[j],  bmn, denom);
      int bl = (int)quantf(fbl[j], bmn, denom);
      pk[j] = (uint32_t)r | ((uint32_t)g << 8) | ((uint32_t)bl << 16);
      uint32_t c2 = (code >> (2 * j)) & 3u;
      int a = (c2 == 1u || c2 == 3u) ? 1 : 0;
      aA[p] = (uint8_t)a;
      a0 += r * a; a1 += g * a; a2 += bl * a; a3 += a;
      t0 += r; t1 += g; t2 += bl;
    }
    red[tid][0] = a0; red[tid][1] = a1; red[tid][2] = a2; red[tid][3] = a3;
    red[tid][4] = t0; red[tid][5] = t1; red[tid][6] = t2; red[tid][7] = 0;
  }
  __syncthreads();
  for (int s = 128; s >= 1; s >>= 1) {
    if (tid < s) {
#pragma unroll
      for (int j = 0; j < 7; j++) red[tid][j] += red[tid + s][j];
    }
    __syncthreads();
  }
  if (tid == 0) {
    slots[blk]  = make_int4(red[0][0], red[0][1], red[0][2], red[0][3]);
    totals[blk] = make_int4(red[0][4], red[0][5], red[0][6], 0);
  }
  __threadfence();
  grid.sync();

  // ---- 5 ICM iterations, alpha ping-pong through global ----
  uint8_t* ain = aA;
  uint8_t* aout = aB;
  for (int k = 0; k < 5; k++) {
    const int4* slotIn = slots + (size_t)k * 256;
    int4* slotOut = slots + (size_t)(k + 1) * 256;
    if (tid < 128) {
      int4 s = slotIn[b * 128 + tid];
      int4 t = totals[b * 128 + tid];
      red[tid][0] = s.x; red[tid][1] = s.y; red[tid][2] = s.z; red[tid][3] = s.w;
      red[tid][4] = t.x; red[tid][5] = t.y; red[tid][6] = t.z; red[tid][7] = 0;
    }
    __syncthreads();
    for (int s = 64; s >= 1; s >>= 1) {
      if (tid < s) {
#pragma unroll
        for (int j = 0; j < 7; j++) red[tid][j] += red[tid + s][j];
      }
      __syncthreads();
    }
    if (tid == 0) {
      int cnt = red[0][3];
      float fden = (float)cnt + 1e-6f;
      float bden = (float)(HW_ - cnt) + 1e-6f;
#pragma unroll
      for (int c = 0; c < 3; c++) {
        fmv[c] = (float)red[0][c] / fden;                   // fg_mean
        bmv[c] = (float)(red[0][4 + c] - red[0][c]) / bden; // bg_mean
      }
    }
    __syncthreads();
    float f0 = fmv[0], f1 = fmv[1], f2 = fmv[2];
    float g0 = bmv[0], g1 = bmv[1], g2 = bmv[2];
    int a0 = 0, a1 = 0, a2 = 0, a3 = 0;
#pragma unroll
    for (int j = 0; j < 8; j++) {
      int p = blk * 2048 + tid + j * 256;
      int pb = p & (HW_ - 1);
      int y = pb >> 9, x = pb & 511;
      uint32_t rgb = pk[j];
      int ri = (int)(rgb & 255u);
      int gi = (int)((rgb >> 8) & 255u);
      int bi = (int)((rgb >> 16) & 255u);
      float i0 = (float)ri, i1 = (float)gi, i2 = (float)bi;  // exact
      int up = ain[p - (y > 0 ? WW : 0)];
      int dn = ain[p + (y < HH - 1 ? WW : 0)];
      int lf = ain[p - (x > 0 ? 1 : 0)];
      int rt = ain[p + (x < WW - 1 ? 1 : 0)];
      float nb = (float)(((up + dn) + lf) + rt) * 0.25f;     // exact in f32
      float pair = 50.0f * ((2.0f * nb) - 1.0f);             // exact in f32
      float t0 = i0 - f0, t1 = i1 - f1, t2 = i2 - f2;
      float df = ((t0 * t0) + (t1 * t1)) + (t2 * t2);
      float u0 = i0 - g0, u1 = i1 - g1, u2 = i2 - g2;
      float db = ((u0 * u0) + (u1 * u1)) + (u2 * u2);
      float score = (db - df) + pair;
      uint32_t c2 = (code >> (2 * j)) & 3u;
      int a;
      if (c2 == 1u) a = 1;                  // fixed FG
      else if (c2 == 2u) a = 0;             // fixed BG
      else a = (score > 0.0f) ? 1 : 0;
      aout[p] = (uint8_t)a;
      if (k == 4) out[p] = (float)a;
      a0 += ri * a; a1 += gi * a; a2 += bi * a; a3 += a;
    }
    red[tid][0] = a0; red[tid][1] = a1; red[tid][2] = a2; red[tid][3] = a3;
    __syncthreads();
    for (int s = 128; s >= 1; s >>= 1) {
      if (tid < s) {
#pragma unroll
        for (int j = 0; j < 4; j++) red[tid][j] += red[tid + s][j];
      }
      __syncthreads();
    }
    if (tid == 0) slotOut[blk] = make_int4(red[0][0], red[0][1], red[0][2], red[0][3]);
    if (k < 4) { __threadfence(); grid.sync(); }
    uint8_t* t = ain; ain = aout; aout = t;
  }
}

extern "C" void kernel_launch(void* const* d_in, const int* in_sizes, int n_in,
                              void* d_out, int out_size, void* d_ws, size_t ws_size,
                              hipStream_t stream) {
  const float* feat = (const float*)d_in[0];   // (2,256,512,512) f32
  const int*   mask = (const int*)d_in[1];     // (2,512,512) i32
  float* out = (float*)d_out;                  // (2,512,512) f32

  // ws layout (~1.05 MB; fully rewritten before any read each launch, poison-safe):
  char* ws = (char*)d_ws;
  uint8_t* aA     = (uint8_t*)(ws);               // 524288
  uint8_t* aB     = (uint8_t*)(ws + 524288);      // 524288
  float2*  mm     = (float2*)(ws + 1048576);      // 256 * 8B  = 2048
  int4*    totals = (int4*)(ws + 1050624);        // 256 * 16B = 4096
  int4*    slots  = (int4*)(ws + 1054720);        // 6*256*16B = 24576

  void* args[] = {(void*)&feat, (void*)&mask, (void*)&out, (void*)&aA, (void*)&aB,
                  (void*)&mm, (void*)&totals, (void*)&slots};
  hipLaunchCooperativeKernel((const void*)k_fused, dim3(256), dim3(256),
                             args, 0, stream);
}

// Round 2
// 590.523 us; speedup vs baseline: 1.4829x; 1.4829x over previous
//
#include <hip/hip_runtime.h>
#include <stdint.h>
#include <stddef.h>

// IEEE-exact ops, no FMA contraction: must reproduce the reference's f32
// arithmetic (binary labels => exact label match, absmax 0).
#pragma clang fp contract(off)

#define HH 512
#define WW 512
#define HW_ 262144             // H*W
#define FEAT_BSTRIDE (256*HW_) // feature batch stride (C=256)

__device__ __forceinline__ float quantf(float f, float mn, float denom) {
  float v = (f - mn) / denom * 255.0f;
  v = floorf(v);
  return fminf(fmaxf(v, 0.0f), 255.0f);
}

// trimap geometry: bh=bw=51, center rows/cols [230,281)
__device__ __forceinline__ bool is_center(int y, int x) {
  return (y >= 230) & (y < 281) & (x >= 230) & (x < 281);
}
__device__ __forceinline__ bool is_border(int y, int x) {
  return (y < 51) | (y >= 461) | (x < 51) | (x >= 461);
}

// wave-wide exact integer sum (64-lane butterfly)
__device__ __forceinline__ int wsum(int v) {
#pragma unroll
  for (int m = 32; m >= 1; m >>= 1) v += __shfl_xor(v, m);
  return v;
}

// K1: per-batch min/max partials over the first 3 channel planes
__global__ __launch_bounds__(256) void k_minmax(const float* __restrict__ feat,
                                                float2* __restrict__ mm) {
  int blk = blockIdx.x, tid = threadIdx.x;
  int b = blk >> 7, ib = blk & 127;
  const float4* base =
      reinterpret_cast<const float4*>(feat + (size_t)b * FEAT_BSTRIDE) + (size_t)ib * 1536;
  float mn = 3.4e38f, mx = -3.4e38f;
#pragma unroll
  for (int j = 0; j < 6; j++) {
    float4 v = base[tid + j * 256];
    mn = fminf(mn, fminf(fminf(v.x, v.y), fminf(v.z, v.w)));
    mx = fmaxf(mx, fmaxf(fmaxf(v.x, v.y), fmaxf(v.z, v.w)));
  }
  __shared__ float smn[256], smx[256];
  smn[tid] = mn; smx[tid] = mx;
  __syncthreads();
  for (int s = 128; s >= 1; s >>= 1) {
    if (tid < s) {
      smn[tid] = fminf(smn[tid], smn[tid + s]);
      smx[tid] = fmaxf(smx[tid], smx[tid + s]);
    }
    __syncthreads();
  }
  if (tid == 0) mm[blk] = make_float2(smn[0], smx[0]);
}

// K2: 512 blocks x 256 thr, 4 consecutive px/thread. Quantize to packed RGB,
// init alpha from mask+trimap, exact-int partials (slot0 fg sums + totals).
__global__ __launch_bounds__(256) void k_init(const float* __restrict__ feat,
                                              const int* __restrict__ mask,
                                              const float2* __restrict__ mm,
                                              uint32_t* __restrict__ packed,
                                              uint8_t* __restrict__ alphaA,
                                              int4* __restrict__ totals,
                                              int4* __restrict__ slot0) {
  int blk = blockIdx.x, tid = threadIdx.x;
  int b = blk >> 8;
  __shared__ float smn[128], smx[128];
  if (tid < 128) { float2 v = mm[b * 128 + tid]; smn[tid] = v.x; smx[tid] = v.y; }
  __syncthreads();
  for (int s = 64; s >= 1; s >>= 1) {
    if (tid < s) {
      smn[tid] = fminf(smn[tid], smn[tid + s]);
      smx[tid] = fmaxf(smx[tid], smx[tid + s]);
    }
    __syncthreads();
  }
  float mn = smn[0];
  float denom = (smx[0] - mn) + 1e-12f;  // f32, matches reference

  int pix = blk * 1024 + tid * 4;
  int pb = pix & (HW_ - 1);
  int y = pb >> 9, xb = pb & 511;
  const float* fbp = feat + (size_t)b * FEAT_BSTRIDE;
  float4 cr = *reinterpret_cast<const float4*>(fbp + pb);
  float4 cg = *reinterpret_cast<const float4*>(fbp + HW_ + pb);
  float4 cb = *reinterpret_cast<const float4*>(fbp + 2 * HW_ + pb);
  int4 mk = *reinterpret_cast<const int4*>(mask + pix);
  float rs[4] = {cr.x, cr.y, cr.z, cr.w};
  float gs[4] = {cg.x, cg.y, cg.z, cg.w};
  float bs[4] = {cb.x, cb.y, cb.z, cb.w};
  int mks[4] = {mk.x, mk.y, mk.z, mk.w};
  int a0 = 0, a1 = 0, a2 = 0, a3 = 0, t0 = 0, t1 = 0, t2 = 0;
  uint32_t pkw[4];
  uint32_t aw = 0;
#pragma unroll
  for (int i = 0; i < 4; i++) {
    int r  = (int)quantf(rs[i], mn, denom);
    int g  = (int)quantf(gs[i], mn, denom);
    int bl = (int)quantf(bs[i], mn, denom);
    pkw[i] = (uint32_t)r | ((uint32_t)g << 8) | ((uint32_t)bl << 16);
    int x = xb + i;
    int a;
    if (is_center(y, x)) a = 1;
    else if (is_border(y, x)) a = 0;
    else a = (mks[i] == 1) ? 1 : 0;
    aw |= (uint32_t)a << (8 * i);
    a0 += r * a; a1 += g * a; a2 += bl * a; a3 += a;
    t0 += r; t1 += g; t2 += bl;
  }
  *reinterpret_cast<uint4*>(packed + pix) = make_uint4(pkw[0], pkw[1], pkw[2], pkw[3]);
  *reinterpret_cast<uint32_t*>(alphaA + pix) = aw;

  a0 = wsum(a0); a1 = wsum(a1); a2 = wsum(a2); a3 = wsum(a3);
  t0 = wsum(t0); t1 = wsum(t1); t2 = wsum(t2);
  __shared__ int xw[4][8];
  int wid = tid >> 6, lane = tid & 63;
  if (lane == 0) {
    xw[wid][0] = a0; xw[wid][1] = a1; xw[wid][2] = a2; xw[wid][3] = a3;
    xw[wid][4] = t0; xw[wid][5] = t1; xw[wid][6] = t2;
  }
  __syncthreads();
  if (tid == 0) {
    int s0 = 0, s1 = 0, s2 = 0, s3 = 0, u0 = 0, u1 = 0, u2 = 0;
#pragma unroll
    for (int w = 0; w < 4; w++) {
      s0 += xw[w][0]; s1 += xw[w][1]; s2 += xw[w][2]; s3 += xw[w][3];
      u0 += xw[w][4]; u1 += xw[w][5]; u2 += xw[w][6];
    }
    slot0[blk]  = make_int4(s0, s1, s2, s3);
    totals[blk] = make_int4(u0, u1, u2, 0);
  }
}

// K3..K7: one ICM iteration. 512 blocks x 256 thr; block owns 2 rows (1024 px),
// thread owns 4 consecutive px. Alpha neighborhood (4 rows) staged in LDS via
// coalesced uint2 loads; neighbor reads are LDS word reads (2-way = free).
__global__ __launch_bounds__(256) void k_relabel(const uint32_t* __restrict__ packed,
                                                 const uint8_t* __restrict__ ain,
                                                 uint8_t* __restrict__ aout,
                                                 const int4* __restrict__ totals,
                                                 const int4* __restrict__ slotIn,
                                                 int4* __restrict__ slotOut,
                                                 float* __restrict__ out,
                                                 int finalIter) {
  int blk = blockIdx.x, tid = threadIdx.x;
  int b = blk >> 8;
  int r0 = (blk & 255) * 2;  // first owned row within batch

  // stage rows r0-1 .. r0+2 (edge-clamped within batch) into LDS
  __shared__ uint32_t arowW[4 * 128];
  {
    int row_i = tid >> 6;
    int src_row = r0 - 1 + row_i;
    src_row = src_row < 0 ? 0 : (src_row > 511 ? 511 : src_row);
    reinterpret_cast<uint2*>(arowW)[tid] = *reinterpret_cast<const uint2*>(
        ain + (size_t)b * HW_ + src_row * 512 + (tid & 63) * 8);
  }

  // deterministic exact-int reduce of this batch's 256 partials
  int4 sv = slotIn[b * 256 + tid];
  int4 tv = totals[b * 256 + tid];
  int v0 = wsum(sv.x), v1 = wsum(sv.y), v2 = wsum(sv.z), v3 = wsum(sv.w);
  int v4 = wsum(tv.x), v5 = wsum(tv.y), v6 = wsum(tv.z);
  __shared__ int xw[4][8];
  int wid = tid >> 6, lane = tid & 63;
  if (lane == 0) {
    xw[wid][0] = v0; xw[wid][1] = v1; xw[wid][2] = v2; xw[wid][3] = v3;
    xw[wid][4] = v4; xw[wid][5] = v5; xw[wid][6] = v6;
  }
  __syncthreads();  // covers arowW staging + xw partials
  // every thread computes the identical means (same ints -> same f32 ops)
  int s0 = xw[0][0] + xw[1][0] + xw[2][0] + xw[3][0];
  int s1 = xw[0][1] + xw[1][1] + xw[2][1] + xw[3][1];
  int s2 = xw[0][2] + xw[1][2] + xw[2][2] + xw[3][2];
  int s3 = xw[0][3] + xw[1][3] + xw[2][3] + xw[3][3];
  int s4 = xw[0][4] + xw[1][4] + xw[2][4] + xw[3][4];
  int s5 = xw[0][5] + xw[1][5] + xw[2][5] + xw[3][5];
  int s6 = xw[0][6] + xw[1][6] + xw[2][6] + xw[3][6];
  int cnt = s3;
  float fden = (float)cnt + 1e-6f;
  float bden = (float)(HW_ - cnt) + 1e-6f;
  float f0 = (float)s0 / fden;            // fg_mean
  float f1 = (float)s1 / fden;
  float f2 = (float)s2 / fden;
  float g0 = (float)(s4 - s0) / bden;     // bg_mean = (total-fg)/nbg
  float g1 = (float)(s5 - s1) / bden;
  float g2 = (float)(s6 - s2) / bden;

  int lr = tid >> 7;       // 0 or 1: owned row
  int q  = tid & 127;      // word index within row
  int x0 = q * 4;
  int yy = r0 + lr;
  uint32_t uw = arowW[lr * 128 + q];        // up row (lds row lr)
  uint32_t cw = arowW[(lr + 1) * 128 + q];  // center row
  uint32_t dw = arowW[(lr + 2) * 128 + q];  // down row
  const uint8_t* arowB = reinterpret_cast<const uint8_t*>(arowW);
  int lfb = arowB[(lr + 1) * 512 + (x0 > 0 ? x0 - 1 : 0)];
  int rtb = arowB[(lr + 1) * 512 + (x0 + 4 < 512 ? x0 + 4 : 511)];

  int pix = b * HW_ + yy * 512 + x0;
  uint4 pk4 = *reinterpret_cast<const uint4*>(packed + pix);
  uint32_t pka[4] = {pk4.x, pk4.y, pk4.z, pk4.w};
  int a0 = 0, a1 = 0, a2 = 0, a3 = 0;
  uint32_t awout = 0;
  float fouts[4];
#pragma unroll
  for (int i = 0; i < 4; i++) {
    uint32_t rgb = pka[i];
    int ri = (int)(rgb & 255u);
    int gi = (int)((rgb >> 8) & 255u);
    int bi = (int)((rgb >> 16) & 255u);
    float i0 = (float)ri, i1 = (float)gi, i2 = (float)bi;  // exact
    int up = (int)((uw >> (8 * i)) & 255u);
    int dn = (int)((dw >> (8 * i)) & 255u);
    int lf = (i == 0) ? lfb : (int)((cw >> (8 * (i - 1))) & 255u);
    int rt = (i == 3) ? rtb : (int)((cw >> (8 * (i + 1))) & 255u);
    float nb = (float)(((up + dn) + lf) + rt) * 0.25f;     // exact in f32
    float pair = 50.0f * ((2.0f * nb) - 1.0f);             // exact in f32
    float t0 = i0 - f0, t1 = i1 - f1, t2 = i2 - f2;
    float df = ((t0 * t0) + (t1 * t1)) + (t2 * t2);
    float u0 = i0 - g0, u1 = i1 - g1, u2 = i2 - g2;
    float db = ((u0 * u0) + (u1 * u1)) + (u2 * u2);
    float score = (db - df) + pair;
    int x = x0 + i;
    int a;
    if (is_center(yy, x)) a = 1;           // fixed FG
    else if (is_border(yy, x)) a = 0;      // fixed BG
    else a = (score > 0.0f) ? 1 : 0;
    awout |= (uint32_t)a << (8 * i);
    fouts[i] = (float)a;
    a0 += ri * a; a1 += gi * a; a2 += bi * a; a3 += a;
  }
  *reinterpret_cast<uint32_t*>(aout + pix) = awout;
  if (finalIter)
    *reinterpret_cast<float4*>(out + pix) = make_float4(fouts[0], fouts[1], fouts[2], fouts[3]);

  a0 = wsum(a0); a1 = wsum(a1); a2 = wsum(a2); a3 = wsum(a3);
  __syncthreads();  // everyone done reading xw before reuse
  if (lane == 0) { xw[wid][0] = a0; xw[wid][1] = a1; xw[wid][2] = a2; xw[wid][3] = a3; }
  __syncthreads();
  if (tid == 0) {
    int o0 = xw[0][0] + xw[1][0] + xw[2][0] + xw[3][0];
    int o1 = xw[0][1] + xw[1][1] + xw[2][1] + xw[3][1];
    int o2 = xw[0][2] + xw[1][2] + xw[2][2] + xw[3][2];
    int o3 = xw[0][3] + xw[1][3] + xw[2][3] + xw[3][3];
    slotOut[blk] = make_int4(o0, o1, o2, o3);
  }
}

extern "C" void kernel_launch(void* const* d_in, const int* in_sizes, int n_in,
                              void* d_out, int out_size, void* d_ws, size_t ws_size,
                              hipStream_t stream) {
  const float* feat = (const float*)d_in[0];   // (2,256,512,512) f32
  const int*   mask = (const int*)d_in[1];     // (2,512,512) i32
  float* out = (float*)d_out;                  // (2,512,512) f32

  // ws layout (~3.2 MB; every byte read is written earlier this launch):
  char* ws = (char*)d_ws;
  uint8_t*  aA     = (uint8_t*)(ws);                 // 524288
  uint8_t*  aB     = (uint8_t*)(ws + 524288);        // 524288
  float2*   mm     = (float2*)(ws + 1048576);        // 256 * 8B   = 2048
  int4*     totals = (int4*)(ws + 1050624);          // 512 * 16B  = 8192
  int4*     slots  = (int4*)(ws + 1058816);          // 6*512*16B  = 49152
  uint32_t* packed = (uint32_t*)(ws + 1107968);      // 524288 * 4B = 2 MB

  k_minmax<<<256, 256, 0, stream>>>(feat, mm);
  k_init<<<512, 256, 0, stream>>>(feat, mask, mm, packed, aA, totals, slots /*slot0*/);

  uint8_t* ain = aA;
  uint8_t* aout_buf = aB;
  for (int k = 0; k < 5; k++) {
    k_relabel<<<512, 256, 0, stream>>>(packed, ain, aout_buf, totals,
                                       slots + (size_t)k * 512,
                                       slots + (size_t)(k + 1) * 512,
                                       out, (k == 4) ? 1 : 0);
    uint8_t* tmp = ain; ain = aout_buf; aout_buf = tmp;
  }
}